// Round 7
// baseline (211.835 us; speedup 1.0000x reference)
//
#include <hip/hip_runtime.h>
#include <hip/hip_bf16.h>

#define BB 8
#define NN 1024
#define DM 78
#define NH 6
#define DK 13
#define NROW 4099                 // 4*1024 + 3
#define QSCL 0.40013158f          // (1/sqrt(13)) * log2(e)
#define SCALE 0.27735009811261457f
#define INV1023 0.000977517106549365f

using bf16 = __hip_bfloat16;
typedef __attribute__((ext_vector_type(8))) short short8;
typedef __attribute__((ext_vector_type(4))) short short4v;
typedef __attribute__((ext_vector_type(4))) float f32x4;

// Native v_exp_f32 (exp2): scores bounded, OCML edge handling unnecessary.
#if __has_builtin(__builtin_amdgcn_exp2f)
#define EXP2(x) __builtin_amdgcn_exp2f(x)
#else
__device__ __forceinline__ float EXP2(float x) {
    float r;
    asm volatile("v_exp_f32 %0, %1\n\ts_nop 1" : "=v"(r) : "v"(x));
    return r;
}
#endif

// S-step MFMA: K=16 (dk=13 padded to 16) — half the pipe time of K=32,
// all 64 lanes active with 8B frags (R5: −9% on att, VGPR 56->36).
#define SMFMA(k, q, c) __builtin_amdgcn_mfma_f32_16x16x16bf16_1k((k), (q), (c), 0, 0, 0)

// ws layout (elems):
//   Qbf  bf16[4][48][1024][16]  (Q * QSCL, cols 13..15 zero)
//   Kbf  bf16[4][48][1024][16]  (cols 13..15 zero)
//   Vt   bf16[4][48][16][1024]  (V^T, KEY-PERMUTED by pi within each 32-key
//                                block so packed exp(S) is directly a PV
//                                A-frag; row 13 = ones -> softmax denom)
//   Qf32 f32 [2][48][1024][13]  (contrastive residual, from MFMA f32 accums)
//   sv   f32 [2][48][13]
//   tok  f32 [3][8][78]
// pi(quad*8+j) = j<4 ? 4*quad+j : 12+4*quad+j  (bijective on [0,32))
#define MATSZ ((size_t)48 * 1024 * 16)

struct PW { const float* w[12]; };

__device__ __forceinline__ unsigned pkbf2(float a, float b) {
    __hip_bfloat162 t = __float22bfloat162_rn(make_float2(a, b));
    return *(unsigned*)&t;
}

union FRAG { unsigned u[4]; short8 s8; };

// ---- projection: ALL 12 mats through the bf16 MFMA path (R6).
// R7: the two serial 64-row column-sum loops (tok @ mat 0, sv @ mats 10,11)
// are parallelized 4-segments-per-column — they were per-block straggler
// tails (64 dependent LDS reads on mostly-idle thread sets).
// R4 lesson kept: W^T pad col pc=40 zero-written (uninit LDS NaN poisons).
__global__ __launch_bounds__(256, 6) void proj_kernel(const float* __restrict__ x,
                                                      const float* __restrict__ y,
                                                      const float* __restrict__ z,
                                                      PW p,
                                                      unsigned* __restrict__ Qbf,
                                                      unsigned* __restrict__ Kbf,
                                                      unsigned* __restrict__ Vt,
                                                      float* __restrict__ Qf32,
                                                      float* __restrict__ sv,
                                                      float* __restrict__ tok) {
    __shared__ unsigned SMEM[6608];     // 26432 B -> 6 blocks/CU
    int bid = blockIdx.x;
    int tid = threadIdx.x;
    int mat = bid >> 7;                 // 0..11: Q(tv,ta,ctv,cta) K(..) V(..)
    int rb = bid & 127;
    const float* src = (mat < 4) ? x : (((mat - 4) & 1) ? z : y);
    const float* sp = src + (size_t)rb * 64 * DM;
    const float* W = p.w[mat];
    int bb = rb >> 4;
    int i0 = (rb & 15) * 64;
    float* CT = (float*)SMEM;           // [64][81], valid after compute phase

    unsigned* ALu = SMEM;               // A bf16 [64 rows][52 u32] (k pad 96+)
    unsigned* WTu = SMEM + 64 * 52;     // W^T bf16 [80 n][41 u32]
    const float2* sp2 = (const float2*)sp;      // tile is contiguous 64*78
    for (int i = tid; i < 64 * 39; i += 256) {
        float2 f2 = sp2[i];                     // elems 2i, 2i+1
        int r = i / 39, pc = i - r * 39;
        ALu[r * 52 + pc] = pkbf2(f2.x, f2.y);
    }
    for (int i = tid; i < 64 * 13; i += 256) {  // zero k 78..103
        int r = i / 13, pc = i - r * 13;
        ALu[r * 52 + 39 + pc] = 0u;
    }
    // coalesced W^T staging; pc 0..40 inclusive (pc=40 zero — R4 lesson)
    for (int i = tid; i < 41 * 80; i += 256) {
        int pc = i / 80, n = i - pc * 80;
        int k0 = pc * 2;
        float a = (n < DM && k0 < DM) ? W[(size_t)k0 * DM + n] : 0.f;
        float bv = (n < DM && k0 + 1 < DM) ? W[(size_t)(k0 + 1) * DM + n] : 0.f;
        WTu[n * 41 + pc] = pkbf2(a, bv);
    }
    __syncthreads();
    // token-0 = column sums of x (bf16 A-tile).  R7: 4 segments/column,
    // 156 threads, 16-row chains (was 39 threads x 64 serial LDS reads).
    if (mat == 0 && tid < 156) {
        int pc = tid % 39, seg = tid / 39;      // seg 0..3
        const unsigned* col = ALu + pc;
        float s0 = 0.f, s1 = 0.f;
        int rA = seg * 16;
#pragma unroll
        for (int r = 0; r < 16; ++r) {
            unsigned u = col[(rA + r) * 52];
            s0 += __uint_as_float(u << 16);
            s1 += __uint_as_float(u & 0xffff0000u);
        }
        atomicAdd(&tok[bb * DM + pc * 2], s0);
        atomicAdd(&tok[bb * DM + pc * 2 + 1], s1);
    }
    int wv = tid >> 6, lane = tid & 63, quad = lane >> 4, lq = lane & 15;
    int r0 = wv * 16;
    const short* ALs = (const short*)ALu;       // row stride 104 bf16
    const short* WTs = (const short*)WTu;       // row stride 82 bf16
    short8 af0 = *(const short8*)(ALs + (r0 + lq) * 104 + quad * 8);
    short8 af1 = *(const short8*)(ALs + (r0 + lq) * 104 + 32 + quad * 8);
    short8 af2 = *(const short8*)(ALs + (r0 + lq) * 104 + 64 + quad * 8);
    const f32x4 zz = {0.f, 0.f, 0.f, 0.f};
    f32x4 acc[5];
#pragma unroll
    for (int n = 0; n < 5; ++n) acc[n] = zz;
#pragma unroll
    for (int n = 0; n < 5; ++n) {
        const short* wb = WTs + (n * 16 + lq) * 82 + quad * 8;
        acc[n] = __builtin_amdgcn_mfma_f32_16x16x32_bf16(
            af0, *(const short8*)wb, acc[n], 0, 0, 0);
        acc[n] = __builtin_amdgcn_mfma_f32_16x16x32_bf16(
            af1, *(const short8*)(wb + 32), acc[n], 0, 0, 0);
        acc[n] = __builtin_amdgcn_mfma_f32_16x16x32_bf16(
            af2, *(const short8*)(wb + 64), acc[n], 0, 0, 0);
    }
    __syncthreads();                // done with ALu/WTu -> reuse as CT
    // D layout: row = r0 + quad*4 + reg, col = n*16 + lq
#pragma unroll
    for (int n = 0; n < 5; ++n) {
        int c = n * 16 + lq;
        if (c < DM) {
#pragma unroll
            for (int r = 0; r < 4; ++r)
                CT[(r0 + quad * 4 + r) * 81 + c] = acc[n][r];
        }
    }
    __syncthreads();
    if (mat < 8) {
        // Q mats 0..3 -> Qbf (scaled); K mats 4..7 -> Kbf
        unsigned* dst = (mat < 4) ? Qbf : Kbf;
        int m4 = (mat < 4) ? mat : mat - 4;
        float scl = (mat < 4) ? QSCL : 1.0f;
        for (int t2 = tid; t2 < NH * 64 * 8; t2 += 256) {
            int hh = t2 >> 9;
            int rem = t2 & 511;
            int r = rem >> 3, cp = rem & 7;
            int c0 = cp * 2, c1 = cp * 2 + 1;
            float a = (c0 < DK) ? CT[r * 81 + hh * DK + c0] * scl : 0.f;
            float bv = (c1 < DK) ? CT[r * 81 + hh * DK + c1] * scl : 0.f;
            dst[(((size_t)m4 * 48 + bb * NH + hh) * 1024 + i0 + r) * 8 + cp] = pkbf2(a, bv);
        }
        if (mat >= 2 && mat < 4) {      // contrastive residual (f32 accum)
            for (int t2 = tid; t2 < 64 * DM; t2 += 256) {
                int r = t2 / DM, c = t2 - r * DM;
                int hh = c / DK, dd = c - hh * DK;
                Qf32[((size_t)(mat - 2) * 48 + bb * NH + hh) * 1024 * DK +
                     (size_t)(i0 + r) * DK + dd] = CT[r * 81 + c];
            }
        }
    } else {
        // V -> Vt, key-permuted by pi within each 32-key block so that
        // att's packed exp(S) registers are directly the PV A-frag.
        for (int t2 = tid; t2 < NH * 16 * 32; t2 += 256) {
            int hh = t2 >> 9;
            int rem = t2 & 511;
            int dd = rem >> 5, cp = rem & 31;
            int pp = (cp & 15) * 2;            // phys pair pos in 32-block
            int b2 = cp >> 4;                  // which 32-block of tile
            int qd = pp >> 3, jj = pp & 7;
            int l0 = b2 * 32 + 4 * qd + (jj < 4 ? jj : 12 + jj);
            float a, bv;
            if (dd < DK) {
                a = CT[l0 * 81 + hh * DK + dd];
                bv = CT[(l0 + 1) * 81 + hh * DK + dd];
            } else if (dd == 13) { a = 1.f; bv = 1.f; }
            else { a = 0.f; bv = 0.f; }
            Vt[(((size_t)(mat - 8) * 48 + bb * NH + hh) * 16 + dd) * 512 +
               (i0 >> 1) + cp] = pkbf2(a, bv);
        }
        // sv column sums.  R7: 3 segments/column, 234 threads, <=22-row
        // chains (was 78 threads x 64 serial LDS reads).
        if (mat >= 10 && tid < 234) {
            int c = tid % 78, seg = tid / 78;   // 0..2
            int rA = seg * 22, rB = (seg == 2) ? 64 : rA + 22;
            float s = 0.f;
            for (int r = rA; r < rB; ++r) s += CT[r * 81 + c];
            int hh = c / DK, dd = c - hh * DK;
            atomicAdd(&sv[((size_t)(mat - 10) * 48 + bb * NH + hh) * DK + dd], s);
        }
    }
}

// ---- MFMA flash attention, ZERO-LDS, K16 S-step (R5 body — best measured;
// R6's depth-2 prefetch was a null at higher VGPR, reverted).
__global__ __launch_bounds__(256) void att_kernel(const bf16* __restrict__ Qbf,
                                                  const bf16* __restrict__ Kbf,
                                                  const bf16* __restrict__ Vt,
                                                  const float* __restrict__ Qf32,
                                                  const float* __restrict__ sv,
                                                  float* __restrict__ tok,
                                                  float* __restrict__ out) {
    int bid = blockIdx.x;
    int qt = (bid >> 3) & 7;
    int ghb = (bid & 7) | ((bid >> 6) << 3);   // 0..191
    int h = ghb % NH;
    int r2 = ghb / NH;
    int b = r2 & 7;
    int g = r2 >> 3;                   // 0=tv 1=ta 2=ctv 3=cta
    int tid = threadIdx.x, wave = tid >> 6, lane = tid & 63;
    int quad = lane >> 4, lq = lane & 15;
    size_t mb = (size_t)g * 48 + b * NH + h;
    int q0 = qt * 64 + wave * 16;
    int q1 = q0 + 512;

    const short* Kp = (const short*)Kbf + mb * 1024 * 16;
    const short* Vp = (const short*)Vt + mb * 16 * 1024 + (size_t)lq * 1024;
    f32x4 OA = {0.f, 0.f, 0.f, 0.f};
    f32x4 OB = {0.f, 0.f, 0.f, 0.f};
    const f32x4 zz = {0.f, 0.f, 0.f, 0.f};

    short4v qfA = *(const short4v*)((const short*)Qbf + (mb * 1024 + q0 + lq) * 16 + quad * 4);
    short4v qfB = *(const short4v*)((const short*)Qbf + (mb * 1024 + q1 + lq) * 16 + quad * 4);
    int ko = quad * 4;                 // 8B frag: k = quad*4 + j, all lanes
    short4v kX0 = *(const short4v*)(Kp + lq * 16 + ko);
    short4v kX1 = *(const short4v*)(Kp + (16 + lq) * 16 + ko);
    short4v kY0 = *(const short4v*)(Kp + (32 + lq) * 16 + ko);
    short4v kY1 = *(const short4v*)(Kp + (48 + lq) * 16 + ko);
    short8 vX = *(const short8*)(Vp + quad * 8);
    short8 vY = *(const short8*)(Vp + 32 + quad * 8);

    const short* Kit = Kp + 64 * 16;   // next-tile base (prefetch)
    const short* Vit = Vp + 64;

    for (int kt = 0; kt < 16; ++kt) {
        // S-MFMAs, both streams (matrix pipe fills while VALU does exps)
        __builtin_amdgcn_s_setprio(1);
        f32x4 SX0 = SMFMA(kX0, qfA, zz);
        f32x4 SX1 = SMFMA(kX1, qfA, zz);
        f32x4 SX2 = SMFMA(kX0, qfB, zz);
        f32x4 SX3 = SMFMA(kX1, qfB, zz);
        f32x4 SY0 = SMFMA(kY0, qfA, zz);
        f32x4 SY1 = SMFMA(kY1, qfA, zz);
        f32x4 SY2 = SMFMA(kY0, qfB, zz);
        f32x4 SY3 = SMFMA(kY1, qfB, zz);
        __builtin_amdgcn_s_setprio(0);
        // prefetch next 64 keys (last iter overruns into adjacent ws:
        // loaded, never used)
        short4v kX0n = *(const short4v*)(Kit + lq * 16 + ko);
        short4v kX1n = *(const short4v*)(Kit + (16 + lq) * 16 + ko);
        short4v kY0n = *(const short4v*)(Kit + (32 + lq) * 16 + ko);
        short4v kY1n = *(const short4v*)(Kit + (48 + lq) * 16 + ko);
        short8 vXn = *(const short8*)(Vit + quad * 8);
        short8 vYn = *(const short8*)(Vit + 32 + quad * 8);

        FRAG aXA, aXB, aYA, aYB;
        aXA.u[0] = pkbf2(EXP2(SX0[0]), EXP2(SX0[1]));
        aXA.u[1] = pkbf2(EXP2(SX0[2]), EXP2(SX0[3]));
        aXA.u[2] = pkbf2(EXP2(SX1[0]), EXP2(SX1[1]));
        aXA.u[3] = pkbf2(EXP2(SX1[2]), EXP2(SX1[3]));
        OA = __builtin_amdgcn_mfma_f32_16x16x32_bf16(aXA.s8, vX, OA, 0, 0, 0);
        aXB.u[0] = pkbf2(EXP2(SX2[0]), EXP2(SX2[1]));
        aXB.u[1] = pkbf2(EXP2(SX2[2]), EXP2(SX2[3]));
        aXB.u[2] = pkbf2(EXP2(SX3[0]), EXP2(SX3[1]));
        aXB.u[3] = pkbf2(EXP2(SX3[2]), EXP2(SX3[3]));
        OB = __builtin_amdgcn_mfma_f32_16x16x32_bf16(aXB.s8, vX, OB, 0, 0, 0);
        aYA.u[0] = pkbf2(EXP2(SY0[0]), EXP2(SY0[1]));
        aYA.u[1] = pkbf2(EXP2(SY0[2]), EXP2(SY0[3]));
        aYA.u[2] = pkbf2(EXP2(SY1[0]), EXP2(SY1[1]));
        aYA.u[3] = pkbf2(EXP2(SY1[2]), EXP2(SY1[3]));
        OA = __builtin_amdgcn_mfma_f32_16x16x32_bf16(aYA.s8, vY, OA, 0, 0, 0);
        aYB.u[0] = pkbf2(EXP2(SY2[0]), EXP2(SY2[1]));
        aYB.u[1] = pkbf2(EXP2(SY2[2]), EXP2(SY2[3]));
        aYB.u[2] = pkbf2(EXP2(SY3[0]), EXP2(SY3[1]));
        aYB.u[3] = pkbf2(EXP2(SY3[2]), EXP2(SY3[3]));
        OB = __builtin_amdgcn_mfma_f32_16x16x32_bf16(aYB.s8, vY, OB, 0, 0, 0);
        kX0 = kX0n; kX1 = kX1n; kY0 = kY0n; kY1 = kY1n; vX = vXn; vY = vYn;
        Kit += 64 * 16; Vit += 64;
    }

    size_t rowbase = (g == 0) ? 0 : (g == 1 ? 2 * NN : (g == 2 ? NN : 3 * NN));
    float lA[4], lB[4];
#pragma unroll
    for (int r = 0; r < 4; ++r) {
        lA[r] = __shfl(OA[r], (lane & 48) | 13, 64);   // ones-column = sum p
        lB[r] = __shfl(OB[r], (lane & 48) | 13, 64);
    }
    float svv = 0.f;
    const float* qf32p = nullptr;
    if (g >= 2) {
        if (lq < DK) svv = sv[((size_t)(g - 2) * 48 + b * NH + h) * DK + lq];
        qf32p = Qf32 + ((size_t)(g - 2) * 48 + b * NH + h) * 1024 * DK + lq;
    }
    float vsum = 0.f;
#pragma unroll
    for (int r = 0; r < 4; ++r) {
        int mA = q0 + quad * 4 + r;
        int mB = q1 + quad * 4 + r;
        float A0 = OA[r] / lA[r];
        float A1 = OB[r] / lB[r];
        float v0, v1;
        if (g < 2) { v0 = A0; v1 = A1; }
        else {
            float qr0 = (lq < DK) ? qf32p[(size_t)mA * DK] : 0.f;
            float qr1 = (lq < DK) ? qf32p[(size_t)mB * DK] : 0.f;
            v0 = qr0 + (svv - A0) * INV1023;
            v1 = qr1 + (svv - A1) * INV1023;
        }
        if (lq < DK) {
            out[((size_t)b * NROW + rowbase + mA) * DM + h * DK + lq] = v0;
            out[((size_t)b * NROW + rowbase + mB) * DM + h * DK + lq] = v1;
            vsum += v0 + v1;
        }
    }
    vsum += __shfl_xor(vsum, 16);
    vsum += __shfl_xor(vsum, 32);
    if (quad == 0 && lq < DK) {
        int tki = (g & 1) ? 2 : 1;
        atomicAdd(&tok[(size_t)tki * (8 * DM) + b * DM + h * DK + lq], vsum);
    }
}

// ---- 3-token MHSA per batch ----
__global__ __launch_bounds__(256) void fused_kernel(const float* __restrict__ tok,
                                                    const float* __restrict__ Wq,
                                                    const float* __restrict__ Wk,
                                                    const float* __restrict__ Wv,
                                                    float* __restrict__ out) {
    __shared__ float T[3 * DM], Qs[3 * DM], Ks[3 * DM], Vs[3 * DM], P[NH * 9];
    int b = blockIdx.x, tid = threadIdx.x;
    if (tid < 234) {
        int t = tid / DM, d = tid - t * DM;
        T[tid] = tok[(size_t)t * (8 * DM) + b * DM + d] * (1.f / NN);
    }
    __syncthreads();
    for (int idx = tid; idx < 702; idx += 256) {
        int mat = idx / 234;
        int rem = idx - mat * 234;
        int t = rem / DM, d = rem - t * DM;
        const float* W = (mat == 0) ? Wq : (mat == 1 ? Wk : Wv);
        float a = 0.f;
        for (int e = 0; e < DM; ++e) a = fmaf(T[t * DM + e], W[(size_t)e * DM + d], a);
        float* dst = (mat == 0) ? Qs : (mat == 1 ? Ks : Vs);
        dst[t * DM + d] = a;
    }
    __syncthreads();
    if (tid < NH * 3) {
        int h = tid / 3, t = tid % 3;
        float s[3];
        for (int k = 0; k < 3; ++k) {
            float a = 0.f;
            for (int d2 = 0; d2 < DK; ++d2)
                a += Qs[t * DM + h * DK + d2] * Ks[k * DM + h * DK + d2];
            s[k] = a * SCALE;
        }
        float mm = fmaxf(s[0], fmaxf(s[1], s[2]));
        float e0 = __expf(s[0] - mm), e1 = __expf(s[1] - mm), e2 = __expf(s[2] - mm);
        float inv = 1.f / (e0 + e1 + e2);
        P[(h * 3 + t) * 3 + 0] = e0 * inv;
        P[(h * 3 + t) * 3 + 1] = e1 * inv;
        P[(h * 3 + t) * 3 + 2] = e2 * inv;
    }
    __syncthreads();
    if (tid < 234) {
        int t = tid / DM, d = tid - t * DM, h = d / DK;
        float a = 0.f;
        for (int k = 0; k < 3; ++k) a += P[(h * 3 + t) * 3 + k] * Vs[k * DM + d];
        out[((size_t)b * NROW + 4 * NN + t) * DM + d] = a;
    }
}

extern "C" void kernel_launch(void* const* d_in, const int* in_sizes, int n_in,
                              void* d_out, int out_size, void* d_ws, size_t ws_size,
                              hipStream_t stream) {
    const float* bigs[3] = {nullptr, nullptr, nullptr};
    const float* w[15];
    int nb = 0, nw = 0;
    for (int i = 0; i < n_in; ++i) {
        if (in_sizes[i] == BB * NN * DM && nb < 3) bigs[nb++] = (const float*)d_in[i];
        else if (in_sizes[i] == DM * DM && nw < 15) w[nw++] = (const float*)d_in[i];
    }
    if (nb < 3 || nw < 15) {
        bigs[0] = (const float*)d_in[0]; bigs[1] = (const float*)d_in[1];
        bigs[2] = (const float*)d_in[2];
        int base = (n_in >= 20) ? 5 : 3;
        for (int i = 0; i < 15; ++i) w[i] = (const float*)d_in[base + i];
    }
    const float* x = bigs[0];
    const float* y = bigs[1];
    const float* z = bigs[2];
    float* out = (float*)d_out;

    bf16* Qbf = (bf16*)d_ws;
    bf16* Kbf = Qbf + 4 * MATSZ;
    bf16* Vt  = Kbf + 4 * MATSZ;
    float* Qf32 = (float*)(Vt + 4 * MATSZ);               // 2*48*1024*13
    float* sv = Qf32 + (size_t)2 * 48 * 1024 * DK;        // 2*48*13 = 1248
    float* tok = sv + 2 * 48 * DK;                        // 3*8*78  = 1872

    PW pp;   // mat -> weight: Q(tv,ta,ctv,cta), K(same), V(same)
    const float* wsel[12] = {w[0], w[3], w[6], w[9],
                             w[1], w[4], w[7], w[10],
                             w[2], w[5], w[8], w[11]};
    for (int i = 0; i < 12; ++i) pp.w[i] = wsel[i];

    // zero the atomic accumulators (sv + tok); memset is graph-capture safe
    hipMemsetAsync(sv, 0, (2 * 48 * DK + 3 * 8 * DM) * sizeof(float), stream);
    proj_kernel<<<1536, 256, 0, stream>>>(x, y, z, pp, (unsigned*)Qbf, (unsigned*)Kbf,
                                          (unsigned*)Vt, Qf32, sv, tok);
    att_kernel<<<4 * BB * NH * 8, 256, 0, stream>>>(Qbf, Kbf, Vt, Qf32, sv, tok, out);
    fused_kernel<<<BB, 256, 0, stream>>>(tok, w[12], w[13], w[14], out);
}

// Round 8
// 209.901 us; speedup vs baseline: 1.0092x; 1.0092x over previous
//
#include <hip/hip_runtime.h>
#include <hip/hip_bf16.h>

#define BB 8
#define NN 1024
#define DM 78
#define NH 6
#define DK 13
#define NROW 4099                 // 4*1024 + 3
#define QSCL 0.40013158f          // (1/sqrt(13)) * log2(e)
#define SCALE 0.27735009811261457f
#define INV1023 0.000977517106549365f

using bf16 = __hip_bfloat16;
typedef __attribute__((ext_vector_type(8))) short short8;
typedef __attribute__((ext_vector_type(4))) short short4v;
typedef __attribute__((ext_vector_type(4))) float f32x4;

// Native v_exp_f32 (kept as fallback; fused_kernel still uses __expf).
#if __has_builtin(__builtin_amdgcn_exp2f)
#define EXP2(x) __builtin_amdgcn_exp2f(x)
#else
__device__ __forceinline__ float EXP2(float x) {
    float r;
    asm volatile("v_exp_f32 %0, %1\n\ts_nop 1" : "=v"(r) : "v"(x));
    return r;
}
#endif

// R8: Schraudolph fast exp2 — 2 full-rate VALU ops (fma + cvt_i32) vs one
// quarter-rate v_exp_f32 (8 cyc).  att's critical path is ~75% exp issue
// (R4/R5/R6 ledger: only cycle cuts move att).  Centered bias constant:
// 127*2^23 - round(log2(1.0614)/2 * 2^23) = 1065353216 - 360118.
// Rel err ±3%, smooth in frac(x); denominator (ones-row PV) uses the SAME
// approximated p -> uniform component cancels in normalization.
__device__ __forceinline__ float FEXP2(float x) {
    int i = (int)fmaf(x, 8388608.f, 1064993098.f);
    return __int_as_float(i);
}

// S-step MFMA: K=16 (dk=13 padded to 16) — half the pipe time of K=32,
// all 64 lanes active with 8B frags (R5: −9% on att, VGPR 56->36).
#define SMFMA(k, q, c) __builtin_amdgcn_mfma_f32_16x16x16bf16_1k((k), (q), (c), 0, 0, 0)

// ws layout (elems):
//   Qbf  bf16[4][48][1024][16]  (Q * QSCL, cols 13..15 zero)
//   Kbf  bf16[4][48][1024][16]  (cols 13..15 zero)
//   Vt   bf16[4][48][16][1024]  (V^T, KEY-PERMUTED by pi within each 32-key
//                                block so packed exp(S) is directly a PV
//                                A-frag; row 13 = ones -> softmax denom)
//   Qf32 f32 [2][48][1024][13]  (contrastive residual, from MFMA f32 accums)
//   sv   f32 [2][48][13]
//   tok  f32 [3][8][78]
// pi(quad*8+j) = j<4 ? 4*quad+j : 12+4*quad+j  (bijective on [0,32))
#define MATSZ ((size_t)48 * 1024 * 16)

struct PW { const float* w[12]; };

__device__ __forceinline__ unsigned pkbf2(float a, float b) {
    __hip_bfloat162 t = __float22bfloat162_rn(make_float2(a, b));
    return *(unsigned*)&t;
}

union FRAG { unsigned u[4]; short8 s8; };

// ---- projection: ALL 12 mats through the bf16 MFMA path (R6).
// R7: parallelized tok/sv column sums.  UNCHANGED in R8 (clean att A/B).
// R4 lesson kept: W^T pad col pc=40 zero-written (uninit LDS NaN poisons).
__global__ __launch_bounds__(256, 6) void proj_kernel(const float* __restrict__ x,
                                                      const float* __restrict__ y,
                                                      const float* __restrict__ z,
                                                      PW p,
                                                      unsigned* __restrict__ Qbf,
                                                      unsigned* __restrict__ Kbf,
                                                      unsigned* __restrict__ Vt,
                                                      float* __restrict__ Qf32,
                                                      float* __restrict__ sv,
                                                      float* __restrict__ tok) {
    __shared__ unsigned SMEM[6608];     // 26432 B -> 6 blocks/CU
    int bid = blockIdx.x;
    int tid = threadIdx.x;
    int mat = bid >> 7;                 // 0..11: Q(tv,ta,ctv,cta) K(..) V(..)
    int rb = bid & 127;
    const float* src = (mat < 4) ? x : (((mat - 4) & 1) ? z : y);
    const float* sp = src + (size_t)rb * 64 * DM;
    const float* W = p.w[mat];
    int bb = rb >> 4;
    int i0 = (rb & 15) * 64;
    float* CT = (float*)SMEM;           // [64][81], valid after compute phase

    unsigned* ALu = SMEM;               // A bf16 [64 rows][52 u32] (k pad 96+)
    unsigned* WTu = SMEM + 64 * 52;     // W^T bf16 [80 n][41 u32]
    const float2* sp2 = (const float2*)sp;      // tile is contiguous 64*78
    for (int i = tid; i < 64 * 39; i += 256) {
        float2 f2 = sp2[i];                     // elems 2i, 2i+1
        int r = i / 39, pc = i - r * 39;
        ALu[r * 52 + pc] = pkbf2(f2.x, f2.y);
    }
    for (int i = tid; i < 64 * 13; i += 256) {  // zero k 78..103
        int r = i / 13, pc = i - r * 13;
        ALu[r * 52 + 39 + pc] = 0u;
    }
    // coalesced W^T staging; pc 0..40 inclusive (pc=40 zero — R4 lesson)
    for (int i = tid; i < 41 * 80; i += 256) {
        int pc = i / 80, n = i - pc * 80;
        int k0 = pc * 2;
        float a = (n < DM && k0 < DM) ? W[(size_t)k0 * DM + n] : 0.f;
        float bv = (n < DM && k0 + 1 < DM) ? W[(size_t)(k0 + 1) * DM + n] : 0.f;
        WTu[n * 41 + pc] = pkbf2(a, bv);
    }
    __syncthreads();
    // token-0 = column sums of x (bf16 A-tile), 4 segments/column.
    if (mat == 0 && tid < 156) {
        int pc = tid % 39, seg = tid / 39;      // seg 0..3
        const unsigned* col = ALu + pc;
        float s0 = 0.f, s1 = 0.f;
        int rA = seg * 16;
#pragma unroll
        for (int r = 0; r < 16; ++r) {
            unsigned u = col[(rA + r) * 52];
            s0 += __uint_as_float(u << 16);
            s1 += __uint_as_float(u & 0xffff0000u);
        }
        atomicAdd(&tok[bb * DM + pc * 2], s0);
        atomicAdd(&tok[bb * DM + pc * 2 + 1], s1);
    }
    int wv = tid >> 6, lane = tid & 63, quad = lane >> 4, lq = lane & 15;
    int r0 = wv * 16;
    const short* ALs = (const short*)ALu;       // row stride 104 bf16
    const short* WTs = (const short*)WTu;       // row stride 82 bf16
    short8 af0 = *(const short8*)(ALs + (r0 + lq) * 104 + quad * 8);
    short8 af1 = *(const short8*)(ALs + (r0 + lq) * 104 + 32 + quad * 8);
    short8 af2 = *(const short8*)(ALs + (r0 + lq) * 104 + 64 + quad * 8);
    const f32x4 zz = {0.f, 0.f, 0.f, 0.f};
    f32x4 acc[5];
#pragma unroll
    for (int n = 0; n < 5; ++n) acc[n] = zz;
#pragma unroll
    for (int n = 0; n < 5; ++n) {
        const short* wb = WTs + (n * 16 + lq) * 82 + quad * 8;
        acc[n] = __builtin_amdgcn_mfma_f32_16x16x32_bf16(
            af0, *(const short8*)wb, acc[n], 0, 0, 0);
        acc[n] = __builtin_amdgcn_mfma_f32_16x16x32_bf16(
            af1, *(const short8*)(wb + 32), acc[n], 0, 0, 0);
        acc[n] = __builtin_amdgcn_mfma_f32_16x16x32_bf16(
            af2, *(const short8*)(wb + 64), acc[n], 0, 0, 0);
    }
    __syncthreads();                // done with ALu/WTu -> reuse as CT
    // D layout: row = r0 + quad*4 + reg, col = n*16 + lq
#pragma unroll
    for (int n = 0; n < 5; ++n) {
        int c = n * 16 + lq;
        if (c < DM) {
#pragma unroll
            for (int r = 0; r < 4; ++r)
                CT[(r0 + quad * 4 + r) * 81 + c] = acc[n][r];
        }
    }
    __syncthreads();
    if (mat < 8) {
        // Q mats 0..3 -> Qbf (scaled); K mats 4..7 -> Kbf
        unsigned* dst = (mat < 4) ? Qbf : Kbf;
        int m4 = (mat < 4) ? mat : mat - 4;
        float scl = (mat < 4) ? QSCL : 1.0f;
        for (int t2 = tid; t2 < NH * 64 * 8; t2 += 256) {
            int hh = t2 >> 9;
            int rem = t2 & 511;
            int r = rem >> 3, cp = rem & 7;
            int c0 = cp * 2, c1 = cp * 2 + 1;
            float a = (c0 < DK) ? CT[r * 81 + hh * DK + c0] * scl : 0.f;
            float bv = (c1 < DK) ? CT[r * 81 + hh * DK + c1] * scl : 0.f;
            dst[(((size_t)m4 * 48 + bb * NH + hh) * 1024 + i0 + r) * 8 + cp] = pkbf2(a, bv);
        }
        if (mat >= 2 && mat < 4) {      // contrastive residual (f32 accum)
            for (int t2 = tid; t2 < 64 * DM; t2 += 256) {
                int r = t2 / DM, c = t2 - r * DM;
                int hh = c / DK, dd = c - hh * DK;
                Qf32[((size_t)(mat - 2) * 48 + bb * NH + hh) * 1024 * DK +
                     (size_t)(i0 + r) * DK + dd] = CT[r * 81 + c];
            }
        }
    } else {
        // V -> Vt, key-permuted by pi within each 32-key block so that
        // att's packed exp(S) registers are directly the PV A-frag.
        for (int t2 = tid; t2 < NH * 16 * 32; t2 += 256) {
            int hh = t2 >> 9;
            int rem = t2 & 511;
            int dd = rem >> 5, cp = rem & 31;
            int pp = (cp & 15) * 2;            // phys pair pos in 32-block
            int b2 = cp >> 4;                  // which 32-block of tile
            int qd = pp >> 3, jj = pp & 7;
            int l0 = b2 * 32 + 4 * qd + (jj < 4 ? jj : 12 + jj);
            float a, bv;
            if (dd < DK) {
                a = CT[l0 * 81 + hh * DK + dd];
                bv = CT[(l0 + 1) * 81 + hh * DK + dd];
            } else if (dd == 13) { a = 1.f; bv = 1.f; }
            else { a = 0.f; bv = 0.f; }
            Vt[(((size_t)(mat - 8) * 48 + bb * NH + hh) * 16 + dd) * 512 +
               (i0 >> 1) + cp] = pkbf2(a, bv);
        }
        // sv column sums, 3 segments/column.
        if (mat >= 10 && tid < 234) {
            int c = tid % 78, seg = tid / 78;   // 0..2
            int rA = seg * 22, rB = (seg == 2) ? 64 : rA + 22;
            float s = 0.f;
            for (int r = rA; r < rB; ++r) s += CT[r * 81 + c];
            int hh = c / DK, dd = c - hh * DK;
            atomicAdd(&sv[((size_t)(mat - 10) * 48 + bb * NH + hh) * DK + dd], s);
        }
    }
}

// ---- MFMA flash attention, ZERO-LDS, K16 S-step.  R8: Schraudolph FEXP2
// replaces v_exp_f32 (the ~75%-of-issue trans block -> full-rate VALU).
__global__ __launch_bounds__(256) void att_kernel(const bf16* __restrict__ Qbf,
                                                  const bf16* __restrict__ Kbf,
                                                  const bf16* __restrict__ Vt,
                                                  const float* __restrict__ Qf32,
                                                  const float* __restrict__ sv,
                                                  float* __restrict__ tok,
                                                  float* __restrict__ out) {
    int bid = blockIdx.x;
    int qt = (bid >> 3) & 7;
    int ghb = (bid & 7) | ((bid >> 6) << 3);   // 0..191
    int h = ghb % NH;
    int r2 = ghb / NH;
    int b = r2 & 7;
    int g = r2 >> 3;                   // 0=tv 1=ta 2=ctv 3=cta
    int tid = threadIdx.x, wave = tid >> 6, lane = tid & 63;
    int quad = lane >> 4, lq = lane & 15;
    size_t mb = (size_t)g * 48 + b * NH + h;
    int q0 = qt * 64 + wave * 16;
    int q1 = q0 + 512;

    const short* Kp = (const short*)Kbf + mb * 1024 * 16;
    const short* Vp = (const short*)Vt + mb * 16 * 1024 + (size_t)lq * 1024;
    f32x4 OA = {0.f, 0.f, 0.f, 0.f};
    f32x4 OB = {0.f, 0.f, 0.f, 0.f};
    const f32x4 zz = {0.f, 0.f, 0.f, 0.f};

    short4v qfA = *(const short4v*)((const short*)Qbf + (mb * 1024 + q0 + lq) * 16 + quad * 4);
    short4v qfB = *(const short4v*)((const short*)Qbf + (mb * 1024 + q1 + lq) * 16 + quad * 4);
    int ko = quad * 4;                 // 8B frag: k = quad*4 + j, all lanes
    short4v kX0 = *(const short4v*)(Kp + lq * 16 + ko);
    short4v kX1 = *(const short4v*)(Kp + (16 + lq) * 16 + ko);
    short4v kY0 = *(const short4v*)(Kp + (32 + lq) * 16 + ko);
    short4v kY1 = *(const short4v*)(Kp + (48 + lq) * 16 + ko);
    short8 vX = *(const short8*)(Vp + quad * 8);
    short8 vY = *(const short8*)(Vp + 32 + quad * 8);

    const short* Kit = Kp + 64 * 16;   // next-tile base (prefetch)
    const short* Vit = Vp + 64;

    for (int kt = 0; kt < 16; ++kt) {
        // S-MFMAs, both streams (matrix pipe fills while VALU packs exps)
        __builtin_amdgcn_s_setprio(1);
        f32x4 SX0 = SMFMA(kX0, qfA, zz);
        f32x4 SX1 = SMFMA(kX1, qfA, zz);
        f32x4 SX2 = SMFMA(kX0, qfB, zz);
        f32x4 SX3 = SMFMA(kX1, qfB, zz);
        f32x4 SY0 = SMFMA(kY0, qfA, zz);
        f32x4 SY1 = SMFMA(kY1, qfA, zz);
        f32x4 SY2 = SMFMA(kY0, qfB, zz);
        f32x4 SY3 = SMFMA(kY1, qfB, zz);
        __builtin_amdgcn_s_setprio(0);
        // prefetch next 64 keys (last iter overruns into adjacent ws:
        // loaded, never used)
        short4v kX0n = *(const short4v*)(Kit + lq * 16 + ko);
        short4v kX1n = *(const short4v*)(Kit + (16 + lq) * 16 + ko);
        short4v kY0n = *(const short4v*)(Kit + (32 + lq) * 16 + ko);
        short4v kY1n = *(const short4v*)(Kit + (48 + lq) * 16 + ko);
        short8 vXn = *(const short8*)(Vit + quad * 8);
        short8 vYn = *(const short8*)(Vit + 32 + quad * 8);

        FRAG aXA, aXB, aYA, aYB;
        aXA.u[0] = pkbf2(FEXP2(SX0[0]), FEXP2(SX0[1]));
        aXA.u[1] = pkbf2(FEXP2(SX0[2]), FEXP2(SX0[3]));
        aXA.u[2] = pkbf2(FEXP2(SX1[0]), FEXP2(SX1[1]));
        aXA.u[3] = pkbf2(FEXP2(SX1[2]), FEXP2(SX1[3]));
        OA = __builtin_amdgcn_mfma_f32_16x16x32_bf16(aXA.s8, vX, OA, 0, 0, 0);
        aXB.u[0] = pkbf2(FEXP2(SX2[0]), FEXP2(SX2[1]));
        aXB.u[1] = pkbf2(FEXP2(SX2[2]), FEXP2(SX2[3]));
        aXB.u[2] = pkbf2(FEXP2(SX3[0]), FEXP2(SX3[1]));
        aXB.u[3] = pkbf2(FEXP2(SX3[2]), FEXP2(SX3[3]));
        OB = __builtin_amdgcn_mfma_f32_16x16x32_bf16(aXB.s8, vX, OB, 0, 0, 0);
        aYA.u[0] = pkbf2(FEXP2(SY0[0]), FEXP2(SY0[1]));
        aYA.u[1] = pkbf2(FEXP2(SY0[2]), FEXP2(SY0[3]));
        aYA.u[2] = pkbf2(FEXP2(SY1[0]), FEXP2(SY1[1]));
        aYA.u[3] = pkbf2(FEXP2(SY1[2]), FEXP2(SY1[3]));
        OA = __builtin_amdgcn_mfma_f32_16x16x32_bf16(aYA.s8, vY, OA, 0, 0, 0);
        aYB.u[0] = pkbf2(FEXP2(SY2[0]), FEXP2(SY2[1]));
        aYB.u[1] = pkbf2(FEXP2(SY2[2]), FEXP2(SY2[3]));
        aYB.u[2] = pkbf2(FEXP2(SY3[0]), FEXP2(SY3[1]));
        aYB.u[3] = pkbf2(FEXP2(SY3[2]), FEXP2(SY3[3]));
        OB = __builtin_amdgcn_mfma_f32_16x16x32_bf16(aYB.s8, vY, OB, 0, 0, 0);
        kX0 = kX0n; kX1 = kX1n; kY0 = kY0n; kY1 = kY1n; vX = vXn; vY = vYn;
        Kit += 64 * 16; Vit += 64;
    }

    size_t rowbase = (g == 0) ? 0 : (g == 1 ? 2 * NN : (g == 2 ? NN : 3 * NN));
    float lA[4], lB[4];
#pragma unroll
    for (int r = 0; r < 4; ++r) {
        lA[r] = __shfl(OA[r], (lane & 48) | 13, 64);   // ones-column = sum p
        lB[r] = __shfl(OB[r], (lane & 48) | 13, 64);
    }
    float svv = 0.f;
    const float* qf32p = nullptr;
    if (g >= 2) {
        if (lq < DK) svv = sv[((size_t)(g - 2) * 48 + b * NH + h) * DK + lq];
        qf32p = Qf32 + ((size_t)(g - 2) * 48 + b * NH + h) * 1024 * DK + lq;
    }
    float vsum = 0.f;
#pragma unroll
    for (int r = 0; r < 4; ++r) {
        int mA = q0 + quad * 4 + r;
        int mB = q1 + quad * 4 + r;
        float A0 = OA[r] / lA[r];
        float A1 = OB[r] / lB[r];
        float v0, v1;
        if (g < 2) { v0 = A0; v1 = A1; }
        else {
            float qr0 = (lq < DK) ? qf32p[(size_t)mA * DK] : 0.f;
            float qr1 = (lq < DK) ? qf32p[(size_t)mB * DK] : 0.f;
            v0 = qr0 + (svv - A0) * INV1023;
            v1 = qr1 + (svv - A1) * INV1023;
        }
        if (lq < DK) {
            out[((size_t)b * NROW + rowbase + mA) * DM + h * DK + lq] = v0;
            out[((size_t)b * NROW + rowbase + mB) * DM + h * DK + lq] = v1;
            vsum += v0 + v1;
        }
    }
    vsum += __shfl_xor(vsum, 16);
    vsum += __shfl_xor(vsum, 32);
    if (quad == 0 && lq < DK) {
        int tki = (g & 1) ? 2 : 1;
        atomicAdd(&tok[(size_t)tki * (8 * DM) + b * DM + h * DK + lq], vsum);
    }
}

// ---- 3-token MHSA per batch (exact __expf — 144 exps total, negligible) ----
__global__ __launch_bounds__(256) void fused_kernel(const float* __restrict__ tok,
                                                    const float* __restrict__ Wq,
                                                    const float* __restrict__ Wk,
                                                    const float* __restrict__ Wv,
                                                    float* __restrict__ out) {
    __shared__ float T[3 * DM], Qs[3 * DM], Ks[3 * DM], Vs[3 * DM], P[NH * 9];
    int b = blockIdx.x, tid = threadIdx.x;
    if (tid < 234) {
        int t = tid / DM, d = tid - t * DM;
        T[tid] = tok[(size_t)t * (8 * DM) + b * DM + d] * (1.f / NN);
    }
    __syncthreads();
    for (int idx = tid; idx < 702; idx += 256) {
        int mat = idx / 234;
        int rem = idx - mat * 234;
        int t = rem / DM, d = rem - t * DM;
        const float* W = (mat == 0) ? Wq : (mat == 1 ? Wk : Wv);
        float a = 0.f;
        for (int e = 0; e < DM; ++e) a = fmaf(T[t * DM + e], W[(size_t)e * DM + d], a);
        float* dst = (mat == 0) ? Qs : (mat == 1 ? Ks : Vs);
        dst[t * DM + d] = a;
    }
    __syncthreads();
    if (tid < NH * 3) {
        int h = tid / 3, t = tid % 3;
        float s[3];
        for (int k = 0; k < 3; ++k) {
            float a = 0.f;
            for (int d2 = 0; d2 < DK; ++d2)
                a += Qs[t * DM + h * DK + d2] * Ks[k * DM + h * DK + d2];
            s[k] = a * SCALE;
        }
        float mm = fmaxf(s[0], fmaxf(s[1], s[2]));
        float e0 = __expf(s[0] - mm), e1 = __expf(s[1] - mm), e2 = __expf(s[2] - mm);
        float inv = 1.f / (e0 + e1 + e2);
        P[(h * 3 + t) * 3 + 0] = e0 * inv;
        P[(h * 3 + t) * 3 + 1] = e1 * inv;
        P[(h * 3 + t) * 3 + 2] = e2 * inv;
    }
    __syncthreads();
    if (tid < 234) {
        int t = tid / DM, d = tid - t * DM, h = d / DK;
        float a = 0.f;
        for (int k = 0; k < 3; ++k) a += P[(h * 3 + t) * 3 + k] * Vs[k * DM + d];
        out[((size_t)b * NROW + 4 * NN + t) * DM + d] = a;
    }
}

extern "C" void kernel_launch(void* const* d_in, const int* in_sizes, int n_in,
                              void* d_out, int out_size, void* d_ws, size_t ws_size,
                              hipStream_t stream) {
    const float* bigs[3] = {nullptr, nullptr, nullptr};
    const float* w[15];
    int nb = 0, nw = 0;
    for (int i = 0; i < n_in; ++i) {
        if (in_sizes[i] == BB * NN * DM && nb < 3) bigs[nb++] = (const float*)d_in[i];
        else if (in_sizes[i] == DM * DM && nw < 15) w[nw++] = (const float*)d_in[i];
    }
    if (nb < 3 || nw < 15) {
        bigs[0] = (const float*)d_in[0]; bigs[1] = (const float*)d_in[1];
        bigs[2] = (const float*)d_in[2];
        int base = (n_in >= 20) ? 5 : 3;
        for (int i = 0; i < 15; ++i) w[i] = (const float*)d_in[base + i];
    }
    const float* x = bigs[0];
    const float* y = bigs[1];
    const float* z = bigs[2];
    float* out = (float*)d_out;

    bf16* Qbf = (bf16*)d_ws;
    bf16* Kbf = Qbf + 4 * MATSZ;
    bf16* Vt  = Kbf + 4 * MATSZ;
    float* Qf32 = (float*)(Vt + 4 * MATSZ);               // 2*48*1024*13
    float* sv = Qf32 + (size_t)2 * 48 * 1024 * DK;        // 2*48*13 = 1248
    float* tok = sv + 2 * 48 * DK;                        // 3*8*78  = 1872

    PW pp;   // mat -> weight: Q(tv,ta,ctv,cta), K(same), V(same)
    const float* wsel[12] = {w[0], w[3], w[6], w[9],
                             w[1], w[4], w[7], w[10],
                             w[2], w[5], w[8], w[11]};
    for (int i = 0; i < 12; ++i) pp.w[i] = wsel[i];

    // zero the atomic accumulators (sv + tok); memset is graph-capture safe
    hipMemsetAsync(sv, 0, (2 * 48 * DK + 3 * 8 * DM) * sizeof(float), stream);
    proj_kernel<<<1536, 256, 0, stream>>>(x, y, z, pp, (unsigned*)Qbf, (unsigned*)Kbf,
                                          (unsigned*)Vt, Qf32, sv, tok);
    att_kernel<<<4 * BB * NH * 8, 256, 0, stream>>>(Qbf, Kbf, Vt, Qf32, sv, tok, out);
    fused_kernel<<<BB, 256, 0, stream>>>(tok, w[12], w[13], w[14], out);
}

// Round 9
// 208.081 us; speedup vs baseline: 1.0180x; 1.0087x over previous
//
#include <hip/hip_runtime.h>
#include <hip/hip_bf16.h>

#define BB 8
#define NN 1024
#define DM 78
#define NH 6
#define DK 13
#define NROW 4099                 // 4*1024 + 3
#define QSCL 0.40013158f          // (1/sqrt(13)) * log2(e)
#define INVQSCL 2.4991779f        // sqrt(13) / log2(e)
#define SCALE 0.27735009811261457f
#define INV1023 0.000977517106549365f

using bf16 = __hip_bfloat16;
typedef __attribute__((ext_vector_type(8))) short short8;
typedef __attribute__((ext_vector_type(4))) short short4v;
typedef __attribute__((ext_vector_type(4))) float f32x4;

// R8: Schraudolph fast exp2 — 2 full-rate VALU ops vs quarter-rate
// v_exp_f32.  Rel err ±3%, smooth in frac(x); the softmax denominator
// (ones-row PV) uses the SAME approximated p -> uniform error cancels.
__device__ __forceinline__ float FEXP2(float x) {
    int i = (int)fmaf(x, 8388608.f, 1064993098.f);
    return __int_as_float(i);
}

// S-step MFMA: K=16 (dk=13 padded to 16) — half the pipe time of K=32,
// all 64 lanes active with 8B frags (R5: −9% on att, VGPR 56->36).
#define SMFMA(k, q, c) __builtin_amdgcn_mfma_f32_16x16x16bf16_1k((k), (q), (c), 0, 0, 0)

// ws layout (elems):
//   Qbf  bf16[4][48][1024][16]  (Q * QSCL, cols 13..15 zero; ALSO the
//                                contrastive-residual source — R9 removed
//                                the redundant Qf32 copy: q is recovered
//                                as bf16(q*QSCL)/QSCL, err ~9e-4 at output)
//   Kbf  bf16[4][48][1024][16]  (cols 13..15 zero)
//   Vt   bf16[4][48][16][1024]  (V^T, KEY-PERMUTED by pi within each 32-key
//                                block so packed exp(S) is directly a PV
//                                A-frag; row 13 = ones -> softmax denom)
//   sv   f32 [2][48][13]
//   tok  f32 [3][8][78]
// pi(quad*8+j) = j<4 ? 4*quad+j : 12+4*quad+j  (bijective on [0,32))
// R9 rationale: at this workload's effective clock (~700 MHz; R8 ledger)
// both big kernels plateau at ~600-700 GB/s HBM traffic — bytes are the
// lever.  Dropping Qf32 cuts 5.1 MB of proj writes + 5.1 MB of att reads.
#define MATSZ ((size_t)48 * 1024 * 16)

struct PW { const float* w[12]; };

__device__ __forceinline__ unsigned pkbf2(float a, float b) {
    __hip_bfloat162 t = __float22bfloat162_rn(make_float2(a, b));
    return *(unsigned*)&t;
}

union FRAG { unsigned u[4]; short8 s8; };

// ---- projection: ALL 12 mats through the bf16 MFMA path (R6).
// R7: parallelized tok/sv column sums.  R9: Qf32 write removed (mats 2,3
// now identical to 0,1).  R4 lesson: W^T pad col pc=40 zero-written.
__global__ __launch_bounds__(256, 6) void proj_kernel(const float* __restrict__ x,
                                                      const float* __restrict__ y,
                                                      const float* __restrict__ z,
                                                      PW p,
                                                      unsigned* __restrict__ Qbf,
                                                      unsigned* __restrict__ Kbf,
                                                      unsigned* __restrict__ Vt,
                                                      float* __restrict__ sv,
                                                      float* __restrict__ tok) {
    __shared__ unsigned SMEM[6608];     // 26432 B -> 6 blocks/CU
    int bid = blockIdx.x;
    int tid = threadIdx.x;
    int mat = bid >> 7;                 // 0..11: Q(tv,ta,ctv,cta) K(..) V(..)
    int rb = bid & 127;
    const float* src = (mat < 4) ? x : (((mat - 4) & 1) ? z : y);
    const float* sp = src + (size_t)rb * 64 * DM;
    const float* W = p.w[mat];
    int bb = rb >> 4;
    int i0 = (rb & 15) * 64;
    float* CT = (float*)SMEM;           // [64][81], valid after compute phase

    unsigned* ALu = SMEM;               // A bf16 [64 rows][52 u32] (k pad 96+)
    unsigned* WTu = SMEM + 64 * 52;     // W^T bf16 [80 n][41 u32]
    const float2* sp2 = (const float2*)sp;      // tile is contiguous 64*78
    for (int i = tid; i < 64 * 39; i += 256) {
        float2 f2 = sp2[i];                     // elems 2i, 2i+1
        int r = i / 39, pc = i - r * 39;
        ALu[r * 52 + pc] = pkbf2(f2.x, f2.y);
    }
    for (int i = tid; i < 64 * 13; i += 256) {  // zero k 78..103
        int r = i / 13, pc = i - r * 13;
        ALu[r * 52 + 39 + pc] = 0u;
    }
    // coalesced W^T staging; pc 0..40 inclusive (pc=40 zero — R4 lesson)
    for (int i = tid; i < 41 * 80; i += 256) {
        int pc = i / 80, n = i - pc * 80;
        int k0 = pc * 2;
        float a = (n < DM && k0 < DM) ? W[(size_t)k0 * DM + n] : 0.f;
        float bv = (n < DM && k0 + 1 < DM) ? W[(size_t)(k0 + 1) * DM + n] : 0.f;
        WTu[n * 41 + pc] = pkbf2(a, bv);
    }
    __syncthreads();
    // token-0 = column sums of x (bf16 A-tile), 4 segments/column.
    if (mat == 0 && tid < 156) {
        int pc = tid % 39, seg = tid / 39;      // seg 0..3
        const unsigned* col = ALu + pc;
        float s0 = 0.f, s1 = 0.f;
        int rA = seg * 16;
#pragma unroll
        for (int r = 0; r < 16; ++r) {
            unsigned u = col[(rA + r) * 52];
            s0 += __uint_as_float(u << 16);
            s1 += __uint_as_float(u & 0xffff0000u);
        }
        atomicAdd(&tok[bb * DM + pc * 2], s0);
        atomicAdd(&tok[bb * DM + pc * 2 + 1], s1);
    }
    int wv = tid >> 6, lane = tid & 63, quad = lane >> 4, lq = lane & 15;
    int r0 = wv * 16;
    const short* ALs = (const short*)ALu;       // row stride 104 bf16
    const short* WTs = (const short*)WTu;       // row stride 82 bf16
    short8 af0 = *(const short8*)(ALs + (r0 + lq) * 104 + quad * 8);
    short8 af1 = *(const short8*)(ALs + (r0 + lq) * 104 + 32 + quad * 8);
    short8 af2 = *(const short8*)(ALs + (r0 + lq) * 104 + 64 + quad * 8);
    const f32x4 zz = {0.f, 0.f, 0.f, 0.f};
    f32x4 acc[5];
#pragma unroll
    for (int n = 0; n < 5; ++n) acc[n] = zz;
#pragma unroll
    for (int n = 0; n < 5; ++n) {
        const short* wb = WTs + (n * 16 + lq) * 82 + quad * 8;
        acc[n] = __builtin_amdgcn_mfma_f32_16x16x32_bf16(
            af0, *(const short8*)wb, acc[n], 0, 0, 0);
        acc[n] = __builtin_amdgcn_mfma_f32_16x16x32_bf16(
            af1, *(const short8*)(wb + 32), acc[n], 0, 0, 0);
        acc[n] = __builtin_amdgcn_mfma_f32_16x16x32_bf16(
            af2, *(const short8*)(wb + 64), acc[n], 0, 0, 0);
    }
    __syncthreads();                // done with ALu/WTu -> reuse as CT
    // D layout: row = r0 + quad*4 + reg, col = n*16 + lq
#pragma unroll
    for (int n = 0; n < 5; ++n) {
        int c = n * 16 + lq;
        if (c < DM) {
#pragma unroll
            for (int r = 0; r < 4; ++r)
                CT[(r0 + quad * 4 + r) * 81 + c] = acc[n][r];
        }
    }
    __syncthreads();
    if (mat < 8) {
        // Q mats 0..3 -> Qbf (scaled); K mats 4..7 -> Kbf
        unsigned* dst = (mat < 4) ? Qbf : Kbf;
        int m4 = (mat < 4) ? mat : mat - 4;
        float scl = (mat < 4) ? QSCL : 1.0f;
        for (int t2 = tid; t2 < NH * 64 * 8; t2 += 256) {
            int hh = t2 >> 9;
            int rem = t2 & 511;
            int r = rem >> 3, cp = rem & 7;
            int c0 = cp * 2, c1 = cp * 2 + 1;
            float a = (c0 < DK) ? CT[r * 81 + hh * DK + c0] * scl : 0.f;
            float bv = (c1 < DK) ? CT[r * 81 + hh * DK + c1] * scl : 0.f;
            dst[(((size_t)m4 * 48 + bb * NH + hh) * 1024 + i0 + r) * 8 + cp] = pkbf2(a, bv);
        }
    } else {
        // V -> Vt, key-permuted by pi within each 32-key block so that
        // att's packed exp(S) registers are directly the PV A-frag.
        for (int t2 = tid; t2 < NH * 16 * 32; t2 += 256) {
            int hh = t2 >> 9;
            int rem = t2 & 511;
            int dd = rem >> 5, cp = rem & 31;
            int pp = (cp & 15) * 2;            // phys pair pos in 32-block
            int b2 = cp >> 4;                  // which 32-block of tile
            int qd = pp >> 3, jj = pp & 7;
            int l0 = b2 * 32 + 4 * qd + (jj < 4 ? jj : 12 + jj);
            float a, bv;
            if (dd < DK) {
                a = CT[l0 * 81 + hh * DK + dd];
                bv = CT[(l0 + 1) * 81 + hh * DK + dd];
            } else if (dd == 13) { a = 1.f; bv = 1.f; }
            else { a = 0.f; bv = 0.f; }
            Vt[(((size_t)(mat - 8) * 48 + bb * NH + hh) * 16 + dd) * 512 +
               (i0 >> 1) + cp] = pkbf2(a, bv);
        }
        // sv column sums, 3 segments/column.
        if (mat >= 10 && tid < 234) {
            int c = tid % 78, seg = tid / 78;   // 0..2
            int rA = seg * 22, rB = (seg == 2) ? 64 : rA + 22;
            float s = 0.f;
            for (int r = rA; r < rB; ++r) s += CT[r * 81 + c];
            int hh = c / DK, dd = c - hh * DK;
            atomicAdd(&sv[((size_t)(mat - 10) * 48 + bb * NH + hh) * DK + dd], s);
        }
    }
}

// ---- MFMA flash attention, ZERO-LDS, K16 S-step, FEXP2.
// R9: contrastive residual q read back from Qbf (bf16, /QSCL) — Qf32 gone.
__global__ __launch_bounds__(256) void att_kernel(const bf16* __restrict__ Qbf,
                                                  const bf16* __restrict__ Kbf,
                                                  const bf16* __restrict__ Vt,
                                                  const float* __restrict__ sv,
                                                  float* __restrict__ tok,
                                                  float* __restrict__ out) {
    int bid = blockIdx.x;
    int qt = (bid >> 3) & 7;
    int ghb = (bid & 7) | ((bid >> 6) << 3);   // 0..191
    int h = ghb % NH;
    int r2 = ghb / NH;
    int b = r2 & 7;
    int g = r2 >> 3;                   // 0=tv 1=ta 2=ctv 3=cta
    int tid = threadIdx.x, wave = tid >> 6, lane = tid & 63;
    int quad = lane >> 4, lq = lane & 15;
    size_t mb = (size_t)g * 48 + b * NH + h;
    int q0 = qt * 64 + wave * 16;
    int q1 = q0 + 512;

    const short* Kp = (const short*)Kbf + mb * 1024 * 16;
    const short* Vp = (const short*)Vt + mb * 16 * 1024 + (size_t)lq * 1024;
    f32x4 OA = {0.f, 0.f, 0.f, 0.f};
    f32x4 OB = {0.f, 0.f, 0.f, 0.f};
    const f32x4 zz = {0.f, 0.f, 0.f, 0.f};

    short4v qfA = *(const short4v*)((const short*)Qbf + (mb * 1024 + q0 + lq) * 16 + quad * 4);
    short4v qfB = *(const short4v*)((const short*)Qbf + (mb * 1024 + q1 + lq) * 16 + quad * 4);
    int ko = quad * 4;                 // 8B frag: k = quad*4 + j, all lanes
    short4v kX0 = *(const short4v*)(Kp + lq * 16 + ko);
    short4v kX1 = *(const short4v*)(Kp + (16 + lq) * 16 + ko);
    short4v kY0 = *(const short4v*)(Kp + (32 + lq) * 16 + ko);
    short4v kY1 = *(const short4v*)(Kp + (48 + lq) * 16 + ko);
    short8 vX = *(const short8*)(Vp + quad * 8);
    short8 vY = *(const short8*)(Vp + 32 + quad * 8);

    const short* Kit = Kp + 64 * 16;   // next-tile base (prefetch)
    const short* Vit = Vp + 64;

    for (int kt = 0; kt < 16; ++kt) {
        // S-MFMAs, both streams (matrix pipe fills while VALU packs exps)
        __builtin_amdgcn_s_setprio(1);
        f32x4 SX0 = SMFMA(kX0, qfA, zz);
        f32x4 SX1 = SMFMA(kX1, qfA, zz);
        f32x4 SX2 = SMFMA(kX0, qfB, zz);
        f32x4 SX3 = SMFMA(kX1, qfB, zz);
        f32x4 SY0 = SMFMA(kY0, qfA, zz);
        f32x4 SY1 = SMFMA(kY1, qfA, zz);
        f32x4 SY2 = SMFMA(kY0, qfB, zz);
        f32x4 SY3 = SMFMA(kY1, qfB, zz);
        __builtin_amdgcn_s_setprio(0);
        // prefetch next 64 keys (last iter overruns into adjacent ws:
        // loaded, never used)
        short4v kX0n = *(const short4v*)(Kit + lq * 16 + ko);
        short4v kX1n = *(const short4v*)(Kit + (16 + lq) * 16 + ko);
        short4v kY0n = *(const short4v*)(Kit + (32 + lq) * 16 + ko);
        short4v kY1n = *(const short4v*)(Kit + (48 + lq) * 16 + ko);
        short8 vXn = *(const short8*)(Vit + quad * 8);
        short8 vYn = *(const short8*)(Vit + 32 + quad * 8);

        FRAG aXA, aXB, aYA, aYB;
        aXA.u[0] = pkbf2(FEXP2(SX0[0]), FEXP2(SX0[1]));
        aXA.u[1] = pkbf2(FEXP2(SX0[2]), FEXP2(SX0[3]));
        aXA.u[2] = pkbf2(FEXP2(SX1[0]), FEXP2(SX1[1]));
        aXA.u[3] = pkbf2(FEXP2(SX1[2]), FEXP2(SX1[3]));
        OA = __builtin_amdgcn_mfma_f32_16x16x32_bf16(aXA.s8, vX, OA, 0, 0, 0);
        aXB.u[0] = pkbf2(FEXP2(SX2[0]), FEXP2(SX2[1]));
        aXB.u[1] = pkbf2(FEXP2(SX2[2]), FEXP2(SX2[3]));
        aXB.u[2] = pkbf2(FEXP2(SX3[0]), FEXP2(SX3[1]));
        aXB.u[3] = pkbf2(FEXP2(SX3[2]), FEXP2(SX3[3]));
        OB = __builtin_amdgcn_mfma_f32_16x16x32_bf16(aXB.s8, vX, OB, 0, 0, 0);
        aYA.u[0] = pkbf2(FEXP2(SY0[0]), FEXP2(SY0[1]));
        aYA.u[1] = pkbf2(FEXP2(SY0[2]), FEXP2(SY0[3]));
        aYA.u[2] = pkbf2(FEXP2(SY1[0]), FEXP2(SY1[1]));
        aYA.u[3] = pkbf2(FEXP2(SY1[2]), FEXP2(SY1[3]));
        OA = __builtin_amdgcn_mfma_f32_16x16x32_bf16(aYA.s8, vY, OA, 0, 0, 0);
        aYB.u[0] = pkbf2(FEXP2(SY2[0]), FEXP2(SY2[1]));
        aYB.u[1] = pkbf2(FEXP2(SY2[2]), FEXP2(SY2[3]));
        aYB.u[2] = pkbf2(FEXP2(SY3[0]), FEXP2(SY3[1]));
        aYB.u[3] = pkbf2(FEXP2(SY3[2]), FEXP2(SY3[3]));
        OB = __builtin_amdgcn_mfma_f32_16x16x32_bf16(aYB.s8, vY, OB, 0, 0, 0);
        kX0 = kX0n; kX1 = kX1n; kY0 = kY0n; kY1 = kY1n; vX = vXn; vY = vYn;
        Kit += 64 * 16; Vit += 64;
    }

    size_t rowbase = (g == 0) ? 0 : (g == 1 ? 2 * NN : (g == 2 ? NN : 3 * NN));
    float lA[4], lB[4];
#pragma unroll
    for (int r = 0; r < 4; ++r) {
        lA[r] = __shfl(OA[r], (lane & 48) | 13, 64);   // ones-column = sum p
        lB[r] = __shfl(OB[r], (lane & 48) | 13, 64);
    }
    float svv = 0.f;
    const unsigned short* qbfp = nullptr;
    if (g >= 2) {
        if (lq < DK) svv = sv[((size_t)(g - 2) * 48 + b * NH + h) * DK + lq];
        qbfp = (const unsigned short*)Qbf + mb * 1024 * 16 + lq;
    }
    float vsum = 0.f;
#pragma unroll
    for (int r = 0; r < 4; ++r) {
        int mA = q0 + quad * 4 + r;
        int mB = q1 + quad * 4 + r;
        float A0 = OA[r] / lA[r];
        float A1 = OB[r] / lB[r];
        float v0, v1;
        if (g < 2) { v0 = A0; v1 = A1; }
        else {
            // q recovered from Qbf: bf16(q*QSCL) -> f32, /QSCL (err ~9e-4)
            float qr0 = 0.f, qr1 = 0.f;
            if (lq < DK) {
                qr0 = __uint_as_float((unsigned)qbfp[(size_t)mA * 16] << 16) * INVQSCL;
                qr1 = __uint_as_float((unsigned)qbfp[(size_t)mB * 16] << 16) * INVQSCL;
            }
            v0 = qr0 + (svv - A0) * INV1023;
            v1 = qr1 + (svv - A1) * INV1023;
        }
        if (lq < DK) {
            out[((size_t)b * NROW + rowbase + mA) * DM + h * DK + lq] = v0;
            out[((size_t)b * NROW + rowbase + mB) * DM + h * DK + lq] = v1;
            vsum += v0 + v1;
        }
    }
    vsum += __shfl_xor(vsum, 16);
    vsum += __shfl_xor(vsum, 32);
    if (quad == 0 && lq < DK) {
        int tki = (g & 1) ? 2 : 1;
        atomicAdd(&tok[(size_t)tki * (8 * DM) + b * DM + h * DK + lq], vsum);
    }
}

// ---- 3-token MHSA per batch (exact __expf — 144 exps total, negligible) ----
__global__ __launch_bounds__(256) void fused_kernel(const float* __restrict__ tok,
                                                    const float* __restrict__ Wq,
                                                    const float* __restrict__ Wk,
                                                    const float* __restrict__ Wv,
                                                    float* __restrict__ out) {
    __shared__ float T[3 * DM], Qs[3 * DM], Ks[3 * DM], Vs[3 * DM], P[NH * 9];
    int b = blockIdx.x, tid = threadIdx.x;
    if (tid < 234) {
        int t = tid / DM, d = tid - t * DM;
        T[tid] = tok[(size_t)t * (8 * DM) + b * DM + d] * (1.f / NN);
    }
    __syncthreads();
    for (int idx = tid; idx < 702; idx += 256) {
        int mat = idx / 234;
        int rem = idx - mat * 234;
        int t = rem / DM, d = rem - t * DM;
        const float* W = (mat == 0) ? Wq : (mat == 1 ? Wk : Wv);
        float a = 0.f;
        for (int e = 0; e < DM; ++e) a = fmaf(T[t * DM + e], W[(size_t)e * DM + d], a);
        float* dst = (mat == 0) ? Qs : (mat == 1 ? Ks : Vs);
        dst[t * DM + d] = a;
    }
    __syncthreads();
    if (tid < NH * 3) {
        int h = tid / 3, t = tid % 3;
        float s[3];
        for (int k = 0; k < 3; ++k) {
            float a = 0.f;
            for (int d2 = 0; d2 < DK; ++d2)
                a += Qs[t * DM + h * DK + d2] * Ks[k * DM + h * DK + d2];
            s[k] = a * SCALE;
        }
        float mm = fmaxf(s[0], fmaxf(s[1], s[2]));
        float e0 = __expf(s[0] - mm), e1 = __expf(s[1] - mm), e2 = __expf(s[2] - mm);
        float inv = 1.f / (e0 + e1 + e2);
        P[(h * 3 + t) * 3 + 0] = e0 * inv;
        P[(h * 3 + t) * 3 + 1] = e1 * inv;
        P[(h * 3 + t) * 3 + 2] = e2 * inv;
    }
    __syncthreads();
    if (tid < 234) {
        int t = tid / DM, d = tid - t * DM, h = d / DK;
        float a = 0.f;
        for (int k = 0; k < 3; ++k) a += P[(h * 3 + t) * 3 + k] * Vs[k * DM + d];
        out[((size_t)b * NROW + 4 * NN + t) * DM + d] = a;
    }
}

extern "C" void kernel_launch(void* const* d_in, const int* in_sizes, int n_in,
                              void* d_out, int out_size, void* d_ws, size_t ws_size,
                              hipStream_t stream) {
    const float* bigs[3] = {nullptr, nullptr, nullptr};
    const float* w[15];
    int nb = 0, nw = 0;
    for (int i = 0; i < n_in; ++i) {
        if (in_sizes[i] == BB * NN * DM && nb < 3) bigs[nb++] = (const float*)d_in[i];
        else if (in_sizes[i] == DM * DM && nw < 15) w[nw++] = (const float*)d_in[i];
    }
    if (nb < 3 || nw < 15) {
        bigs[0] = (const float*)d_in[0]; bigs[1] = (const float*)d_in[1];
        bigs[2] = (const float*)d_in[2];
        int base = (n_in >= 20) ? 5 : 3;
        for (int i = 0; i < 15; ++i) w[i] = (const float*)d_in[base + i];
    }
    const float* x = bigs[0];
    const float* y = bigs[1];
    const float* z = bigs[2];
    float* out = (float*)d_out;

    bf16* Qbf = (bf16*)d_ws;
    bf16* Kbf = Qbf + 4 * MATSZ;
    bf16* Vt  = Kbf + 4 * MATSZ;
    float* sv = (float*)(Vt + 4 * MATSZ);                 // 2*48*13 = 1248
    float* tok = sv + 2 * 48 * DK;                        // 3*8*78  = 1872

    PW pp;   // mat -> weight: Q(tv,ta,ctv,cta), K(same), V(same)
    const float* wsel[12] = {w[0], w[3], w[6], w[9],
                             w[1], w[4], w[7], w[10],
                             w[2], w[5], w[8], w[11]};
    for (int i = 0; i < 12; ++i) pp.w[i] = wsel[i];

    // zero the atomic accumulators (sv + tok); memset is graph-capture safe
    hipMemsetAsync(sv, 0, (2 * 48 * DK + 3 * 8 * DM) * sizeof(float), stream);
    proj_kernel<<<1536, 256, 0, stream>>>(x, y, z, pp, (unsigned*)Qbf, (unsigned*)Kbf,
                                          (unsigned*)Vt, sv, tok);
    att_kernel<<<4 * BB * NH * 8, 256, 0, stream>>>(Qbf, Kbf, Vt, sv, tok, out);
    fused_kernel<<<BB, 256, 0, stream>>>(tok, w[12], w[13], w[14], out);
}